// Round 1
// baseline (541.050 us; speedup 1.0000x reference)
//
#include <hip/hip_runtime.h>

typedef float v4f __attribute__((ext_vector_type(4)));

#define N_NODES 50000
#define N_ROWS  800000
#define C 128

// W1f = W1[0:128,:] + W1[128:256,:]  (concat([g,g]) @ W1 == g @ W1f)
__global__ __launch_bounds__(256) void prep_w1f(const float* __restrict__ W1,
                                                float* __restrict__ W1f) {
    int i = blockIdx.x * 256 + threadIdx.x;
    if (i < C * C) W1f[i] = W1[i] + W1[C * C + i];
}

// Per-node fused: z = relu(x @ W1f + b1) @ W2 + b2
// Block = 256 threads, tile = 64 rows x 128 cols. Thread (rg,cg) computes
// rows {rg, rg+16, rg+32, rg+48} x cols [8*cg, 8*cg+8). LDS buffer [64][132]
// (pad 132 => x-read banks (4r+k)%32 conflict-free) shared between x-tile and
// h-tile (barrier-separated reuse keeps LDS at 33 KB).
__global__ __launch_bounds__(256) void node_kernel(
    const float* __restrict__ x, const float* __restrict__ W1f,
    const float* __restrict__ b1, const float* __restrict__ W2,
    const float* __restrict__ b2, float* __restrict__ z)
{
    __shared__ float smem[64 * 132];
    const int tid = threadIdx.x;
    const int cg  = tid & 15;
    const int rg  = tid >> 4;
    const int c0  = cg * 8;
    const int node0 = blockIdx.x * 64;

    // stage x tile (coalesced float4 reads, row-major LDS with pad)
    {
        int r  = tid >> 5;            // 0..7
        int c4 = (tid & 31) * 4;      // 0..124
        #pragma unroll
        for (int it = 0; it < 8; ++it, r += 8) {
            int gr = node0 + r;
            if (gr >= N_NODES) gr = N_NODES - 1;   // clamp: safe read, write guarded later
            v4f v = *reinterpret_cast<const v4f*>(&x[(long)gr * C + c4]);
            *reinterpret_cast<v4f*>(&smem[r * 132 + c4]) = v;
        }
    }
    __syncthreads();

    float acc[4][8];
    #pragma unroll
    for (int m = 0; m < 4; ++m)
        #pragma unroll
        for (int j = 0; j < 8; ++j) acc[m][j] = 0.f;

    // GEMM1: h = x @ W1f
    #pragma unroll 4
    for (int k = 0; k < C; ++k) {
        v4f w0 = *reinterpret_cast<const v4f*>(&W1f[k * C + c0]);
        v4f w1 = *reinterpret_cast<const v4f*>(&W1f[k * C + c0 + 4]);
        #pragma unroll
        for (int m = 0; m < 4; ++m) {
            float xv = smem[(rg + 16 * m) * 132 + k];
            acc[m][0] += xv * w0.x; acc[m][1] += xv * w0.y;
            acc[m][2] += xv * w0.z; acc[m][3] += xv * w0.w;
            acc[m][4] += xv * w1.x; acc[m][5] += xv * w1.y;
            acc[m][6] += xv * w1.z; acc[m][7] += xv * w1.w;
        }
    }

    float bb[8];
    #pragma unroll
    for (int j = 0; j < 8; ++j) bb[j] = b1[c0 + j];

    __syncthreads();   // all x reads complete before overwriting buffer with h
    #pragma unroll
    for (int m = 0; m < 4; ++m) {
        int r = rg + 16 * m;
        v4f h0, h1;
        h0.x = acc[m][0] + bb[0]; h0.y = acc[m][1] + bb[1];
        h0.z = acc[m][2] + bb[2]; h0.w = acc[m][3] + bb[3];
        h1.x = acc[m][4] + bb[4]; h1.y = acc[m][5] + bb[5];
        h1.z = acc[m][6] + bb[6]; h1.w = acc[m][7] + bb[7];
        h0.x = h0.x > 0.f ? h0.x : 0.f; h0.y = h0.y > 0.f ? h0.y : 0.f;
        h0.z = h0.z > 0.f ? h0.z : 0.f; h0.w = h0.w > 0.f ? h0.w : 0.f;
        h1.x = h1.x > 0.f ? h1.x : 0.f; h1.y = h1.y > 0.f ? h1.y : 0.f;
        h1.z = h1.z > 0.f ? h1.z : 0.f; h1.w = h1.w > 0.f ? h1.w : 0.f;
        *reinterpret_cast<v4f*>(&smem[r * 132 + c0])     = h0;
        *reinterpret_cast<v4f*>(&smem[r * 132 + c0 + 4]) = h1;
    }
    __syncthreads();

    #pragma unroll
    for (int m = 0; m < 4; ++m)
        #pragma unroll
        for (int j = 0; j < 8; ++j) acc[m][j] = 0.f;

    // GEMM2: z = h @ W2
    #pragma unroll 4
    for (int k = 0; k < C; ++k) {
        v4f w0 = *reinterpret_cast<const v4f*>(&W2[k * C + c0]);
        v4f w1 = *reinterpret_cast<const v4f*>(&W2[k * C + c0 + 4]);
        #pragma unroll
        for (int m = 0; m < 4; ++m) {
            float hv = smem[(rg + 16 * m) * 132 + k];
            acc[m][0] += hv * w0.x; acc[m][1] += hv * w0.y;
            acc[m][2] += hv * w0.z; acc[m][3] += hv * w0.w;
            acc[m][4] += hv * w1.x; acc[m][5] += hv * w1.y;
            acc[m][6] += hv * w1.z; acc[m][7] += hv * w1.w;
        }
    }

    #pragma unroll
    for (int j = 0; j < 8; ++j) bb[j] = b2[c0 + j];

    #pragma unroll
    for (int m = 0; m < 4; ++m) {
        int gr = node0 + rg + 16 * m;
        if (gr < N_NODES) {
            v4f o0, o1;
            o0.x = acc[m][0] + bb[0]; o0.y = acc[m][1] + bb[1];
            o0.z = acc[m][2] + bb[2]; o0.w = acc[m][3] + bb[3];
            o1.x = acc[m][4] + bb[4]; o1.y = acc[m][5] + bb[5];
            o1.z = acc[m][6] + bb[6]; o1.w = acc[m][7] + bb[7];
            *reinterpret_cast<v4f*>(&z[(long)gr * C + c0])     = o0;
            *reinterpret_cast<v4f*>(&z[(long)gr * C + c0 + 4]) = o1;
        }
    }
}

// y[e] = z[idx[e]]  — float4 vectorized; 32 float4 per row; non-temporal
// stores so the 410 MB y-stream doesn't evict the 25.6 MB z from L2.
__global__ __launch_bounds__(256) void gather_kernel(
    const v4f* __restrict__ z4, const int* __restrict__ idx,
    v4f* __restrict__ y4)
{
    long i = (long)blockIdx.x * 256 + threadIdx.x;   // over N_ROWS*32 float4s
    int row = (int)(i >> 5);
    int c   = (int)(i & 31);
    int n = idx[row];
    v4f v = z4[(long)n * 32 + c];
    __builtin_nontemporal_store(v, &y4[i]);
}

extern "C" void kernel_launch(void* const* d_in, const int* in_sizes, int n_in,
                              void* d_out, int out_size, void* d_ws, size_t ws_size,
                              hipStream_t stream) {
    const float* x   = (const float*)d_in[0];
    const int*   idx = (const int*)d_in[1];
    const float* W1  = (const float*)d_in[2];
    const float* b1  = (const float*)d_in[3];
    const float* W2  = (const float*)d_in[4];
    const float* b2  = (const float*)d_in[5];
    float* y = (float*)d_out;

    float* z   = (float*)d_ws;                 // 50000*128 fp32 = 25.6 MB
    float* W1f = z + (size_t)N_NODES * C;      // +64 KB

    hipLaunchKernelGGL(prep_w1f, dim3(64), dim3(256), 0, stream, W1, W1f);
    hipLaunchKernelGGL(node_kernel, dim3((N_NODES + 63) / 64), dim3(256), 0, stream,
                       x, W1f, b1, W2, b2, z);
    hipLaunchKernelGGL(gather_kernel, dim3((N_ROWS * 32) / 256), dim3(256), 0, stream,
                       (const v4f*)z, idx, (v4f*)y);
}